// Round 5
// baseline (5797.862 us; speedup 1.0000x reference)
//
#include <hip/hip_runtime.h>

#define B_DIM 8
#define CIN   32
#define COUT  64
#define KCH   4
#define F_DIM 256   // B_DIM*CIN
#define CHUNK 128   // f's per chunk (= 4 batches); 2 chunks
#define NCHUNK 2
#define MB    8     // rows per einsum block

// ---------------------------------------------------------------- utilities

__global__ __launch_bounds__(256) void zero_kernel(int* p, int n) {
    int i = blockIdx.x * 256 + threadIdx.x;
    if (i < n) p[i] = 0;
}

__global__ __launch_bounds__(256) void hist_kernel(const int* __restrict__ L_row,
                                                   int* __restrict__ cnt, int nnz) {
    int i = blockIdx.x * 256 + threadIdx.x;
    if (i < nnz) atomicAdd(&cnt[L_row[i]], 1);
}

// single-block exclusive scan, 8 elements/thread.
__global__ __launch_bounds__(1024) void scan_kernel(int* __restrict__ cursor,
                                                    int* __restrict__ row_ptr, int M) {
    __shared__ int wsum[16];
    __shared__ int sbase_s;
    int tid = threadIdx.x, lane = tid & 63, wid = tid >> 6;
    if (tid == 0) sbase_s = 0;
    __syncthreads();
    int nchunk = (M + 8191) / 8192;
    for (int ch = 0; ch < nchunk; ch++) {
        int i0 = ch * 8192 + tid * 8;
        int v[8];
        if (i0 + 8 <= M) {
            int4 a = *(const int4*)&cursor[i0];
            int4 b = *(const int4*)&cursor[i0 + 4];
            v[0]=a.x; v[1]=a.y; v[2]=a.z; v[3]=a.w;
            v[4]=b.x; v[5]=b.y; v[6]=b.z; v[7]=b.w;
        } else {
            #pragma unroll
            for (int t = 0; t < 8; t++) v[t] = (i0 + t < M) ? cursor[i0 + t] : 0;
        }
        int s = 0;
        #pragma unroll
        for (int t = 0; t < 8; t++) { int tmp = v[t]; v[t] = s; s += tmp; }
        int sc = s;
        #pragma unroll
        for (int d = 1; d < 64; d <<= 1) {
            int t = __shfl_up(sc, d);
            if (lane >= d) sc += t;
        }
        if (lane == 63) wsum[wid] = sc;
        __syncthreads();
        if (wid == 0) {
            int w = (lane < 16) ? wsum[lane] : 0;
            #pragma unroll
            for (int d = 1; d < 16; d <<= 1) {
                int t = __shfl_up(w, d);
                if (lane >= d) w += t;
            }
            if (lane < 16) wsum[lane] = w;
        }
        __syncthreads();
        int base = sbase_s + ((wid > 0) ? wsum[wid - 1] : 0) + (sc - s);
        #pragma unroll
        for (int t = 0; t < 8; t++) {
            int idx = i0 + t;
            if (idx < M) { int e = base + v[t]; row_ptr[idx] = e; cursor[idx] = e; }
        }
        __syncthreads();
        if (tid == 0) sbase_s += wsum[15];
        __syncthreads();
    }
    if (tid == 0) row_ptr[M] = sbase_s;
}

// pack (col, val) int2 pairs in CSR order
__global__ __launch_bounds__(256) void scatter_kernel(
        const int* __restrict__ L_row, const int* __restrict__ L_col,
        const float* __restrict__ L_val,
        int* __restrict__ cursor, int2* __restrict__ cv, int nnz) {
    int i = blockIdx.x * 256 + threadIdx.x;
    if (i < nnz) {
        int r = L_row[i];
        int p = atomicAdd(&cursor[r], 1);
        int2 e;
        e.x = L_col[i];
        e.y = __float_as_int(L_val[i]);
        cv[p] = e;
    }
}

// theta (COUT,CIN,K) -> th_t[(k*CIN+i)*COUT + o]
__global__ __launch_bounds__(256) void th_prep_kernel(const float* __restrict__ theta,
                                                      float* __restrict__ th_t) {
    int idx = blockIdx.x * 256 + threadIdx.x;
    if (idx < KCH * CIN * COUT) {
        int o = idx & 63;
        int rest = idx >> 6;
        int i = rest & 31;
        int k = rest >> 5;
        th_t[idx] = theta[(o * CIN + i) * KCH + k];
    }
}

// x rows [f0+by*64, f0+by*64+64) -> X0c[m*CHUNK + by*64 + fl]: 64x64 LDS transpose
__global__ __launch_bounds__(256) void transpose_kernel(const float* __restrict__ x,
                                                        float* __restrict__ X0c,
                                                        int M, int f0) {
    __shared__ float tile[64][65];
    int tid = threadIdx.x;
    int ml = tid & 63;
    int fl0 = tid >> 6;               // 0..3
    int m0 = blockIdx.x * 64;
    int fb = blockIdx.y * 64;
    #pragma unroll 4
    for (int ff = fl0; ff < 64; ff += 4) {
        int m = m0 + ml;
        tile[ff][ml] = (m < M) ? x[(size_t)(f0 + fb + ff) * M + m] : 0.f;
    }
    __syncthreads();
    int fl = tid & 63;
    #pragma unroll 4
    for (int mm = fl0; mm < 64; mm += 4) {
        int m = m0 + mm;
        if (m < M) X0c[m * CHUNK + fb + fl] = tile[fl][mm];
    }
}

// ---------------------------------------------------------------- SpMM core
// One wave gathers one CSR row over a 128-float chunk: lane owns float2 at
// Xi[c*128 + lane*2]. 8-deep software pipeline (4 KB in flight per wave).
__device__ __forceinline__ float2 gather_row_c(const int2* __restrict__ cv,
                                               int start, int end,
                                               const float2* __restrict__ Xi2,
                                               int lane) {
    float ax = 0.f, ay = 0.f;
    for (int base = start; base < end; base += 64) {
        int e = base + lane;
        int cl = 0; float vl = 0.f;
        if (e < end) { int2 p = cv[e]; cl = p.x; vl = __int_as_float(p.y); }
        int cnt = min(64, end - base);
        int c0=__shfl(cl,0), c1=__shfl(cl,1), c2=__shfl(cl,2), c3=__shfl(cl,3);
        int c4=__shfl(cl,4), c5=__shfl(cl,5), c6=__shfl(cl,6), c7=__shfl(cl,7);
        float2 h0 = Xi2[c0 * 64 + lane];
        float2 h1 = Xi2[c1 * 64 + lane];
        float2 h2 = Xi2[c2 * 64 + lane];
        float2 h3 = Xi2[c3 * 64 + lane];
        float2 h4 = Xi2[c4 * 64 + lane];
        float2 h5 = Xi2[c5 * 64 + lane];
        float2 h6 = Xi2[c6 * 64 + lane];
        float2 h7 = Xi2[c7 * 64 + lane];
        for (int j = 0; j < cnt; j += 8) {
            float2 g0=h0, g1=h1, g2=h2, g3=h3, g4=h4, g5=h5, g6=h6, g7=h7;
            int jn = j + 8;
            if (jn < cnt) {
                int d0=__shfl(cl,jn),   d1=__shfl(cl,jn+1), d2=__shfl(cl,jn+2), d3=__shfl(cl,jn+3);
                int d4=__shfl(cl,jn+4), d5=__shfl(cl,jn+5), d6=__shfl(cl,jn+6), d7=__shfl(cl,jn+7);
                h0 = Xi2[d0 * 64 + lane];
                h1 = Xi2[d1 * 64 + lane];
                h2 = Xi2[d2 * 64 + lane];
                h3 = Xi2[d3 * 64 + lane];
                h4 = Xi2[d4 * 64 + lane];
                h5 = Xi2[d5 * 64 + lane];
                h6 = Xi2[d6 * 64 + lane];
                h7 = Xi2[d7 * 64 + lane];
            }
            float v0=__shfl(vl,j),   v1=__shfl(vl,j+1), v2=__shfl(vl,j+2), v3=__shfl(vl,j+3);
            float v4=__shfl(vl,j+4), v5=__shfl(vl,j+5), v6=__shfl(vl,j+6), v7=__shfl(vl,j+7);
            ax += v0*g0.x; ay += v0*g0.y;
            ax += v1*g1.x; ay += v1*g1.y;
            ax += v2*g2.x; ay += v2*g2.y;
            ax += v3*g3.x; ay += v3*g3.y;
            ax += v4*g4.x; ay += v4*g4.y;
            ax += v5*g5.x; ay += v5*g5.y;
            ax += v6*g6.x; ay += v6*g6.y;
            ax += v7*g7.x; ay += v7*g7.y;
        }
    }
    float2 r; r.x = ax; r.y = ay;
    return r;
}

// MODE 1: Xout = L*Xin ; MODE 2: Xout = 2*L*Xin - Xprev   (per 128-f chunk)
template <int MODE>
__global__ __launch_bounds__(256) void spmm_kernel(
        const int* __restrict__ row_ptr, const int2* __restrict__ cv,
        const float* __restrict__ Xin, const float* __restrict__ Xprev,
        float* __restrict__ Xout, int M) {
    int lane = threadIdx.x & 63, wid = threadIdx.x >> 6;
    int m = blockIdx.x * 4 + wid;
    if (m >= M) return;
    int start = row_ptr[m], end = row_ptr[m + 1];
    float2 acc = gather_row_c(cv, start, end, (const float2*)Xin, lane);
    float2 outv;
    if (MODE == 1) {
        outv = acc;
    } else {
        float2 p = ((const float2*)Xprev)[m * 64 + lane];
        outv.x = 2.f * acc.x - p.x;
        outv.y = 2.f * acc.y - p.y;
    }
    ((float2*)Xout)[m * 64 + lane] = outv;
}

// ---------------------------------------------------------------- einsum
// Per chunk (4 batches): y[b,o,m] = bias[o] + sum_k sum_i th[k][i][o]*Xk[m][bsel*32+i]
// Block = 256 threads, MB=8 rows. Thread: r=tid&7, og=(tid>>3)&7, bsel=tid>>6.
__device__ __forceinline__ void accum_k(const float* __restrict__ thk,
                                        const float* __restrict__ xr,
                                        int og, float acc[8]) {
    #pragma unroll
    for (int i4 = 0; i4 < 8; i4++) {
        float4 xa = *(const float4*)&xr[i4 * 4];
        float xs[4] = {xa.x, xa.y, xa.z, xa.w};
        #pragma unroll
        for (int c = 0; c < 4; c++) {
            const float* tp = &thk[(i4 * 4 + c) * COUT + og * 8];
            float4 t0 = *(const float4*)tp;
            float4 t1 = *(const float4*)(tp + 4);
            float a = xs[c];
            acc[0] += a * t0.x; acc[1] += a * t0.y; acc[2] += a * t0.z; acc[3] += a * t0.w;
            acc[4] += a * t1.x; acc[5] += a * t1.y; acc[6] += a * t1.z; acc[7] += a * t1.w;
        }
    }
}

__global__ __launch_bounds__(256) void einsum_kernel(
        const float* __restrict__ X0, const float* __restrict__ X1,
        const float* __restrict__ X2, const float* __restrict__ X3,
        const float* __restrict__ th_t, const float* __restrict__ bias,
        float* __restrict__ y, int M, int bbase) {
    __shared__ __align__(16) float th_lds[KCH * CIN * COUT];   // 32 KB
    __shared__ __align__(16) float x_lds[MB][132];             // 4.2 KB (per-k reuse)

    int tid = threadIdx.x;
    #pragma unroll
    for (int i = tid * 4; i < KCH * CIN * COUT; i += 1024)
        *(float4*)&th_lds[i] = *(const float4*)&th_t[i];

    int r = tid & 7, h = tid >> 3;
    int og = h & 7, bsel = h >> 3;       // bsel = tid>>6, wave-uniform
    int m = blockIdx.x * MB + r;

    int rr = tid >> 5, ff = (tid & 31) * 4;   // staging coords
    int mm = blockIdx.x * MB + rr;

    float acc[8] = {0.f, 0.f, 0.f, 0.f, 0.f, 0.f, 0.f, 0.f};

    #pragma unroll
    for (int k = 0; k < KCH; k++) {
        const float* Xs = (k == 0) ? X0 : (k == 1) ? X1 : (k == 2) ? X2 : X3;
        __syncthreads();                       // prior reads of x_lds done
        float4 v = {0.f, 0.f, 0.f, 0.f};
        if (mm < M) v = *(const float4*)&Xs[mm * CHUNK + ff];
        *(float4*)&x_lds[rr][ff] = v;
        __syncthreads();                       // staging (and th for k=0) visible
        accum_k(&th_lds[k * CIN * COUT], &x_lds[r][bsel * 32], og, acc);
    }

    if (m < M) {
        int b = bbase + bsel;
        #pragma unroll
        for (int oo = 0; oo < 8; oo++) {
            int o = og * 8 + oo;
            y[(size_t)(b * COUT + o) * M + m] = acc[oo] + bias[o];
        }
    }
}

// ---------------------------------------------------------------- launcher

extern "C" void kernel_launch(void* const* d_in, const int* in_sizes, int n_in,
                              void* d_out, int out_size, void* d_ws, size_t ws_size,
                              hipStream_t stream) {
    const float* x     = (const float*)d_in[0];
    const int*   L_row = (const int*)d_in[1];
    const int*   L_col = (const int*)d_in[2];
    const float* L_val = (const float*)d_in[3];
    const float* theta = (const float*)d_in[4];
    const float* bias  = (const float*)d_in[5];
    float* y = (float*)d_out;

    int M   = in_sizes[0] / F_DIM;   // 100000
    int NNZ = in_sizes[1];           // 1600000
    int Mpad = (M + 4 + 3) & ~3;     // row_ptr region padded to 16B multiple

    // workspace layout (chunk buffers reused across 2 sequential chunks)
    size_t MC = (size_t)M * CHUNK;
    float* X0      = (float*)d_ws;
    float* X1      = X0 + MC;
    float* X2      = X1 + MC;
    float* X3      = X2 + MC;
    float* th_t    = X3 + MC;                       // 8192 floats
    int*   row_ptr = (int*)(th_t + KCH * CIN * COUT);
    int*   cursor  = row_ptr + Mpad;
    int2*  cv      = (int2*)(cursor + ((M + 3) & ~3));

    // CSR build (once)
    zero_kernel<<<(M + 255) / 256, 256, 0, stream>>>(cursor, M);
    hist_kernel<<<(NNZ + 255) / 256, 256, 0, stream>>>(L_row, cursor, NNZ);
    scan_kernel<<<1, 1024, 0, stream>>>(cursor, row_ptr, M);
    scatter_kernel<<<(NNZ + 255) / 256, 256, 0, stream>>>(L_row, L_col, L_val,
                                                          cursor, cv, NNZ);
    th_prep_kernel<<<(KCH * CIN * COUT + 255) / 256, 256, 0, stream>>>(theta, th_t);

    // 2 sequential chunks of 128 f's (4 batches each); per-chunk hot gather
    // operand (51 MB) + edges (13 MB) stays L3-resident.
    for (int c = 0; c < NCHUNK; c++) {
        transpose_kernel<<<dim3((M + 63) / 64, CHUNK / 64), 256, 0, stream>>>(
            x, X0, M, CHUNK * c);
        spmm_kernel<1><<<(M + 3) / 4, 256, 0, stream>>>(row_ptr, cv, X0, nullptr, X1, M);
        spmm_kernel<2><<<(M + 3) / 4, 256, 0, stream>>>(row_ptr, cv, X1, X0, X2, M);
        spmm_kernel<2><<<(M + 3) / 4, 256, 0, stream>>>(row_ptr, cv, X2, X1, X3, M);
        einsum_kernel<<<(M + MB - 1) / MB, 256, 0, stream>>>(X0, X1, X2, X3,
                                                             th_t, bias, y, M, 4 * c);
    }
}

// Round 7
// 1319.760 us; speedup vs baseline: 4.3931x; 4.3931x over previous
//
#include <hip/hip_runtime.h>

#define B_DIM 8
#define CIN   32
#define COUT  64
#define KCH   4
#define F_DIM 256   // B_DIM*CIN
#define CHUNK 128   // f's per chunk (= 4 batches); 2 chunks
#define NCHUNK 2
#define MB    8     // rows per einsum block

// ---------------------------------------------------------------- utilities

__global__ __launch_bounds__(256) void zero_kernel(int* p, int n) {
    int i = blockIdx.x * 256 + threadIdx.x;
    if (i < n) p[i] = 0;
}

__global__ __launch_bounds__(256) void hist_kernel(const int* __restrict__ L_row,
                                                   int* __restrict__ cnt, int nnz) {
    int i = blockIdx.x * 256 + threadIdx.x;
    if (i < nnz) atomicAdd(&cnt[L_row[i]], 1);
}

// single-block exclusive scan, 8 elements/thread.
__global__ __launch_bounds__(1024) void scan_kernel(int* __restrict__ cursor,
                                                    int* __restrict__ row_ptr, int M) {
    __shared__ int wsum[16];
    __shared__ int sbase_s;
    int tid = threadIdx.x, lane = tid & 63, wid = tid >> 6;
    if (tid == 0) sbase_s = 0;
    __syncthreads();
    int nchunk = (M + 8191) / 8192;
    for (int ch = 0; ch < nchunk; ch++) {
        int i0 = ch * 8192 + tid * 8;
        int v[8];
        if (i0 + 8 <= M) {
            int4 a = *(const int4*)&cursor[i0];
            int4 b = *(const int4*)&cursor[i0 + 4];
            v[0]=a.x; v[1]=a.y; v[2]=a.z; v[3]=a.w;
            v[4]=b.x; v[5]=b.y; v[6]=b.z; v[7]=b.w;
        } else {
            #pragma unroll
            for (int t = 0; t < 8; t++) v[t] = (i0 + t < M) ? cursor[i0 + t] : 0;
        }
        int s = 0;
        #pragma unroll
        for (int t = 0; t < 8; t++) { int tmp = v[t]; v[t] = s; s += tmp; }
        int sc = s;
        #pragma unroll
        for (int d = 1; d < 64; d <<= 1) {
            int t = __shfl_up(sc, d);
            if (lane >= d) sc += t;
        }
        if (lane == 63) wsum[wid] = sc;
        __syncthreads();
        if (wid == 0) {
            int w = (lane < 16) ? wsum[lane] : 0;
            #pragma unroll
            for (int d = 1; d < 16; d <<= 1) {
                int t = __shfl_up(w, d);
                if (lane >= d) w += t;
            }
            if (lane < 16) wsum[lane] = w;
        }
        __syncthreads();
        int base = sbase_s + ((wid > 0) ? wsum[wid - 1] : 0) + (sc - s);
        #pragma unroll
        for (int t = 0; t < 8; t++) {
            int idx = i0 + t;
            if (idx < M) { int e = base + v[t]; row_ptr[idx] = e; cursor[idx] = e; }
        }
        __syncthreads();
        if (tid == 0) sbase_s += wsum[15];
        __syncthreads();
    }
    if (tid == 0) row_ptr[M] = sbase_s;
}

// pack (col, val) int2 pairs in CSR order
__global__ __launch_bounds__(256) void scatter_kernel(
        const int* __restrict__ L_row, const int* __restrict__ L_col,
        const float* __restrict__ L_val,
        int* __restrict__ cursor, int2* __restrict__ cv, int nnz) {
    int i = blockIdx.x * 256 + threadIdx.x;
    if (i < nnz) {
        int r = L_row[i];
        int p = atomicAdd(&cursor[r], 1);
        int2 e;
        e.x = L_col[i];
        e.y = __float_as_int(L_val[i]);
        cv[p] = e;
    }
}

// theta (COUT,CIN,K) -> th_t[(k*CIN+i)*COUT + o]
__global__ __launch_bounds__(256) void th_prep_kernel(const float* __restrict__ theta,
                                                      float* __restrict__ th_t) {
    int idx = blockIdx.x * 256 + threadIdx.x;
    if (idx < KCH * CIN * COUT) {
        int o = idx & 63;
        int rest = idx >> 6;
        int i = rest & 31;
        int k = rest >> 5;
        th_t[idx] = theta[(o * CIN + i) * KCH + k];
    }
}

// x rows [f0+by*64, f0+by*64+64) -> X0c[m*CHUNK + by*64 + fl]: 64x64 LDS transpose
__global__ __launch_bounds__(256) void transpose_kernel(const float* __restrict__ x,
                                                        float* __restrict__ X0c,
                                                        int M, int f0) {
    __shared__ float tile[64][65];
    int tid = threadIdx.x;
    int ml = tid & 63;
    int fl0 = tid >> 6;               // 0..3
    int m0 = blockIdx.x * 64;
    int fb = blockIdx.y * 64;
    #pragma unroll 4
    for (int ff = fl0; ff < 64; ff += 4) {
        int m = m0 + ml;
        tile[ff][ml] = (m < M) ? x[(size_t)(f0 + fb + ff) * M + m] : 0.f;
    }
    __syncthreads();
    int fl = tid & 63;
    #pragma unroll 4
    for (int mm = fl0; mm < 64; mm += 4) {
        int m = m0 + mm;
        if (m < M) X0c[m * CHUNK + fb + fl] = tile[fl][mm];
    }
}

// ---------------------------------------------------------------- SpMM core
// One wave gathers one CSR row over a 128-float chunk: lane owns float2 at
// Xi[c*128 + lane*2]. 8-deep software pipeline (4 KB in flight per wave).
__device__ __forceinline__ float2 gather_row_c(const int2* __restrict__ cv,
                                               int start, int end,
                                               const float2* __restrict__ Xi2,
                                               int lane) {
    float ax = 0.f, ay = 0.f;
    for (int base = start; base < end; base += 64) {
        int e = base + lane;
        int cl = 0; float vl = 0.f;
        if (e < end) { int2 p = cv[e]; cl = p.x; vl = __int_as_float(p.y); }
        int cnt = min(64, end - base);
        int c0=__shfl(cl,0), c1=__shfl(cl,1), c2=__shfl(cl,2), c3=__shfl(cl,3);
        int c4=__shfl(cl,4), c5=__shfl(cl,5), c6=__shfl(cl,6), c7=__shfl(cl,7);
        float2 h0 = Xi2[c0 * 64 + lane];
        float2 h1 = Xi2[c1 * 64 + lane];
        float2 h2 = Xi2[c2 * 64 + lane];
        float2 h3 = Xi2[c3 * 64 + lane];
        float2 h4 = Xi2[c4 * 64 + lane];
        float2 h5 = Xi2[c5 * 64 + lane];
        float2 h6 = Xi2[c6 * 64 + lane];
        float2 h7 = Xi2[c7 * 64 + lane];
        for (int j = 0; j < cnt; j += 8) {
            float2 g0=h0, g1=h1, g2=h2, g3=h3, g4=h4, g5=h5, g6=h6, g7=h7;
            int jn = j + 8;
            if (jn < cnt) {
                int d0=__shfl(cl,jn),   d1=__shfl(cl,jn+1), d2=__shfl(cl,jn+2), d3=__shfl(cl,jn+3);
                int d4=__shfl(cl,jn+4), d5=__shfl(cl,jn+5), d6=__shfl(cl,jn+6), d7=__shfl(cl,jn+7);
                h0 = Xi2[d0 * 64 + lane];
                h1 = Xi2[d1 * 64 + lane];
                h2 = Xi2[d2 * 64 + lane];
                h3 = Xi2[d3 * 64 + lane];
                h4 = Xi2[d4 * 64 + lane];
                h5 = Xi2[d5 * 64 + lane];
                h6 = Xi2[d6 * 64 + lane];
                h7 = Xi2[d7 * 64 + lane];
            }
            float v0=__shfl(vl,j),   v1=__shfl(vl,j+1), v2=__shfl(vl,j+2), v3=__shfl(vl,j+3);
            float v4=__shfl(vl,j+4), v5=__shfl(vl,j+5), v6=__shfl(vl,j+6), v7=__shfl(vl,j+7);
            ax += v0*g0.x; ay += v0*g0.y;
            ax += v1*g1.x; ay += v1*g1.y;
            ax += v2*g2.x; ay += v2*g2.y;
            ax += v3*g3.x; ay += v3*g3.y;
            ax += v4*g4.x; ay += v4*g4.y;
            ax += v5*g5.x; ay += v5*g5.y;
            ax += v6*g6.x; ay += v6*g6.y;
            ax += v7*g7.x; ay += v7*g7.y;
        }
    }
    float2 r; r.x = ax; r.y = ay;
    return r;
}

// MODE 1: Xout = L*Xin ; MODE 2: Xout = 2*L*Xin - Xprev   (per 128-f chunk)
template <int MODE>
__global__ __launch_bounds__(256) void spmm_kernel(
        const int* __restrict__ row_ptr, const int2* __restrict__ cv,
        const float* __restrict__ Xin, const float* __restrict__ Xprev,
        float* __restrict__ Xout, int M) {
    int lane = threadIdx.x & 63, wid = threadIdx.x >> 6;
    int m = blockIdx.x * 4 + wid;
    if (m >= M) return;
    int start = row_ptr[m], end = row_ptr[m + 1];
    float2 acc = gather_row_c(cv, start, end, (const float2*)Xin, lane);
    float2 outv;
    if (MODE == 1) {
        outv = acc;
    } else {
        float2 p = ((const float2*)Xprev)[m * 64 + lane];
        outv.x = 2.f * acc.x - p.x;
        outv.y = 2.f * acc.y - p.y;
    }
    ((float2*)Xout)[m * 64 + lane] = outv;
}

// ---------------------------------------------------------------- einsum
// Per chunk (4 batches): y[b,o,m] = bias[o] + sum_k sum_i th[k][i][o]*Xk[m][bsel*32+i]
// Block = 256 threads, MB=8 rows. Thread: r=tid&7, og=(tid>>3)&7, bsel=tid>>6.
// k-loop is NOT unrolled (rounds 3/5 lesson: unrolling across barrier-separated
// phases merges live ranges -> 256 VGPR spill). launch_bounds caps at 128 VGPR.
__device__ __forceinline__ void accum_k(const float* __restrict__ thk,
                                        const float* __restrict__ xr,
                                        int og, float acc[8]) {
    #pragma unroll
    for (int i4 = 0; i4 < 8; i4++) {
        float4 xa = *(const float4*)&xr[i4 * 4];
        float xs[4] = {xa.x, xa.y, xa.z, xa.w};
        #pragma unroll
        for (int c = 0; c < 4; c++) {
            const float* tp = &thk[(i4 * 4 + c) * COUT + og * 8];
            float4 t0 = *(const float4*)tp;
            float4 t1 = *(const float4*)(tp + 4);
            float a = xs[c];
            acc[0] += a * t0.x; acc[1] += a * t0.y; acc[2] += a * t0.z; acc[3] += a * t0.w;
            acc[4] += a * t1.x; acc[5] += a * t1.y; acc[6] += a * t1.z; acc[7] += a * t1.w;
        }
    }
}

__global__ __launch_bounds__(256, 4) void einsum_kernel(
        const float* __restrict__ Xbase,   // X0..X3 contiguous, stride MC
        size_t MC,
        const float* __restrict__ th_t, const float* __restrict__ bias,
        float* __restrict__ y, int M, int bbase) {
    __shared__ __align__(16) float th_lds[KCH * CIN * COUT];   // 32 KB
    __shared__ __align__(16) float x_lds[MB][132];             // 4.2 KB (per-k reuse)

    int tid = threadIdx.x;
    for (int i = tid * 4; i < KCH * CIN * COUT; i += 1024)
        *(float4*)&th_lds[i] = *(const float4*)&th_t[i];

    int r = tid & 7, h = tid >> 3;
    int og = h & 7, bsel = h >> 3;       // bsel = tid>>6, wave-uniform
    int m = blockIdx.x * MB + r;

    int rr = tid >> 5, ff = (tid & 31) * 4;   // staging coords
    int mm = blockIdx.x * MB + rr;

    float acc[8] = {0.f, 0.f, 0.f, 0.f, 0.f, 0.f, 0.f, 0.f};

    #pragma unroll 1
    for (int k = 0; k < KCH; k++) {
        const float* Xs = Xbase + (size_t)k * MC;   // arithmetic, no select chain
        __syncthreads();                       // prior reads of x_lds done
        float4 v = {0.f, 0.f, 0.f, 0.f};
        if (mm < M) v = *(const float4*)&Xs[(size_t)mm * CHUNK + ff];
        *(float4*)&x_lds[rr][ff] = v;
        __syncthreads();                       // staging (and th for k=0) visible
        accum_k(&th_lds[k * CIN * COUT], &x_lds[r][bsel * 32], og, acc);
    }

    if (m < M) {
        int b = bbase + bsel;
        #pragma unroll
        for (int oo = 0; oo < 8; oo++) {
            int o = og * 8 + oo;
            y[(size_t)(b * COUT + o) * M + m] = acc[oo] + bias[o];
        }
    }
}

// ---------------------------------------------------------------- launcher

extern "C" void kernel_launch(void* const* d_in, const int* in_sizes, int n_in,
                              void* d_out, int out_size, void* d_ws, size_t ws_size,
                              hipStream_t stream) {
    const float* x     = (const float*)d_in[0];
    const int*   L_row = (const int*)d_in[1];
    const int*   L_col = (const int*)d_in[2];
    const float* L_val = (const float*)d_in[3];
    const float* theta = (const float*)d_in[4];
    const float* bias  = (const float*)d_in[5];
    float* y = (float*)d_out;

    int M   = in_sizes[0] / F_DIM;   // 100000
    int NNZ = in_sizes[1];           // 1600000
    int Mpad = (M + 4 + 3) & ~3;     // row_ptr region padded to 16B multiple

    // workspace layout (chunk buffers reused across 2 sequential chunks)
    size_t MC = (size_t)M * CHUNK;
    float* X0      = (float*)d_ws;
    float* X1      = X0 + MC;
    float* X2      = X1 + MC;
    float* X3      = X2 + MC;
    float* th_t    = X3 + MC;                       // 8192 floats
    int*   row_ptr = (int*)(th_t + KCH * CIN * COUT);
    int*   cursor  = row_ptr + Mpad;
    int2*  cv      = (int2*)(cursor + ((M + 3) & ~3));

    // CSR build (once)
    zero_kernel<<<(M + 255) / 256, 256, 0, stream>>>(cursor, M);
    hist_kernel<<<(NNZ + 255) / 256, 256, 0, stream>>>(L_row, cursor, NNZ);
    scan_kernel<<<1, 1024, 0, stream>>>(cursor, row_ptr, M);
    scatter_kernel<<<(NNZ + 255) / 256, 256, 0, stream>>>(L_row, L_col, L_val,
                                                          cursor, cv, NNZ);
    th_prep_kernel<<<(KCH * CIN * COUT + 255) / 256, 256, 0, stream>>>(theta, th_t);

    // 2 sequential chunks of 128 f's (4 batches each); per-chunk hot gather
    // operand (51 MB) + edges (13 MB) stays L3-resident.
    for (int c = 0; c < NCHUNK; c++) {
        transpose_kernel<<<dim3((M + 63) / 64, CHUNK / 64), 256, 0, stream>>>(
            x, X0, M, CHUNK * c);
        spmm_kernel<1><<<(M + 3) / 4, 256, 0, stream>>>(row_ptr, cv, X0, nullptr, X1, M);
        spmm_kernel<2><<<(M + 3) / 4, 256, 0, stream>>>(row_ptr, cv, X1, X0, X2, M);
        spmm_kernel<2><<<(M + 3) / 4, 256, 0, stream>>>(row_ptr, cv, X2, X1, X3, M);
        einsum_kernel<<<(M + MB - 1) / MB, 256, 0, stream>>>(X0, MC, th_t, bias,
                                                             y, M, 4 * c);
    }
}

// Round 9
// 963.344 us; speedup vs baseline: 6.0185x; 1.3700x over previous
//
#include <hip/hip_runtime.h>
#include <hip/hip_bf16.h>

typedef unsigned short u16;

#define B_DIM 8
#define CIN   32
#define COUT  64
#define KCH   4
#define F_DIM 256   // B_DIM*CIN; full F per pass now (bf16 -> 512 B/row)

// bf16 helpers
__device__ __forceinline__ float bf2f(u16 u) {
    return __uint_as_float(((unsigned)u) << 16);
}
__device__ __forceinline__ u16 f2bf(float f) {
    union { __hip_bfloat16 h; u16 u; } c;
    c.h = __float2bfloat16(f);           // RNE
    return c.u;
}

// ---------------------------------------------------------------- utilities

__global__ __launch_bounds__(256) void zero_kernel(int* p, int n) {
    int i = blockIdx.x * 256 + threadIdx.x;
    if (i < n) p[i] = 0;
}

__global__ __launch_bounds__(256) void hist_kernel(const int* __restrict__ L_row,
                                                   int* __restrict__ cnt, int nnz) {
    int i = blockIdx.x * 256 + threadIdx.x;
    if (i < nnz) atomicAdd(&cnt[L_row[i]], 1);
}

// single-block exclusive scan, 8 elements/thread.
__global__ __launch_bounds__(1024) void scan_kernel(int* __restrict__ cursor,
                                                    int* __restrict__ row_ptr, int M) {
    __shared__ int wsum[16];
    __shared__ int sbase_s;
    int tid = threadIdx.x, lane = tid & 63, wid = tid >> 6;
    if (tid == 0) sbase_s = 0;
    __syncthreads();
    int nchunk = (M + 8191) / 8192;
    for (int ch = 0; ch < nchunk; ch++) {
        int i0 = ch * 8192 + tid * 8;
        int v[8];
        if (i0 + 8 <= M) {
            int4 a = *(const int4*)&cursor[i0];
            int4 b = *(const int4*)&cursor[i0 + 4];
            v[0]=a.x; v[1]=a.y; v[2]=a.z; v[3]=a.w;
            v[4]=b.x; v[5]=b.y; v[6]=b.z; v[7]=b.w;
        } else {
            #pragma unroll
            for (int t = 0; t < 8; t++) v[t] = (i0 + t < M) ? cursor[i0 + t] : 0;
        }
        int s = 0;
        #pragma unroll
        for (int t = 0; t < 8; t++) { int tmp = v[t]; v[t] = s; s += tmp; }
        int sc = s;
        #pragma unroll
        for (int d = 1; d < 64; d <<= 1) {
            int t = __shfl_up(sc, d);
            if (lane >= d) sc += t;
        }
        if (lane == 63) wsum[wid] = sc;
        __syncthreads();
        if (wid == 0) {
            int w = (lane < 16) ? wsum[lane] : 0;
            #pragma unroll
            for (int d = 1; d < 16; d <<= 1) {
                int t = __shfl_up(w, d);
                if (lane >= d) w += t;
            }
            if (lane < 16) wsum[lane] = w;
        }
        __syncthreads();
        int base = sbase_s + ((wid > 0) ? wsum[wid - 1] : 0) + (sc - s);
        #pragma unroll
        for (int t = 0; t < 8; t++) {
            int idx = i0 + t;
            if (idx < M) { int e = base + v[t]; row_ptr[idx] = e; cursor[idx] = e; }
        }
        __syncthreads();
        if (tid == 0) sbase_s += wsum[15];
        __syncthreads();
    }
    if (tid == 0) row_ptr[M] = sbase_s;
}

// pack (col, val) int2 pairs in CSR order
__global__ __launch_bounds__(256) void scatter_kernel(
        const int* __restrict__ L_row, const int* __restrict__ L_col,
        const float* __restrict__ L_val,
        int* __restrict__ cursor, int2* __restrict__ cv, int nnz) {
    int i = blockIdx.x * 256 + threadIdx.x;
    if (i < nnz) {
        int r = L_row[i];
        int p = atomicAdd(&cursor[r], 1);
        int2 e;
        e.x = L_col[i];
        e.y = __float_as_int(L_val[i]);
        cv[p] = e;
    }
}

// theta (COUT,CIN,K) -> th_t[(k*CIN+i)*COUT + o]
__global__ __launch_bounds__(256) void th_prep_kernel(const float* __restrict__ theta,
                                                      float* __restrict__ th_t) {
    int idx = blockIdx.x * 256 + threadIdx.x;
    if (idx < KCH * CIN * COUT) {
        int o = idx & 63;
        int rest = idx >> 6;
        int i = rest & 31;
        int k = rest >> 5;
        th_t[idx] = theta[(o * CIN + i) * KCH + k];
    }
}

// x (256,M) fp32 -> X0 (M,256) bf16: 64x64 LDS tile transpose, 4 f-blocks
__global__ __launch_bounds__(256) void transpose_kernel(const float* __restrict__ x,
                                                        u16* __restrict__ X0c, int M) {
    __shared__ float tile[64][65];
    int tid = threadIdx.x;
    int ml = tid & 63;
    int fl0 = tid >> 6;               // 0..3
    int m0 = blockIdx.x * 64;
    int fb = blockIdx.y * 64;
    #pragma unroll 4
    for (int ff = fl0; ff < 64; ff += 4) {
        int m = m0 + ml;
        tile[ff][ml] = (m < M) ? x[(size_t)(fb + ff) * M + m] : 0.f;
    }
    __syncthreads();
    int fl = tid & 63;
    #pragma unroll 4
    for (int mm = fl0; mm < 64; mm += 4) {
        int m = m0 + mm;
        if (m < M) X0c[(size_t)m * F_DIM + fb + fl] = f2bf(tile[fl][mm]);
    }
}

// ---------------------------------------------------------------- SpMM core
// One wave gathers one CSR row over 256 bf16: lane owns ushort4 (8 B) at
// Xi[c*64 + lane]. 8-deep software pipeline (4 KB in flight per wave).
__device__ __forceinline__ float4 gather_row_bf(const int2* __restrict__ cv,
                                                int start, int end,
                                                const ushort4* __restrict__ Xi,
                                                int lane) {
    float ax = 0.f, ay = 0.f, az = 0.f, aw = 0.f;
    for (int base = start; base < end; base += 64) {
        int e = base + lane;
        int cl = 0; float vl = 0.f;
        if (e < end) { int2 p = cv[e]; cl = p.x; vl = __int_as_float(p.y); }
        int cnt = min(64, end - base);
        int c0=__shfl(cl,0), c1=__shfl(cl,1), c2=__shfl(cl,2), c3=__shfl(cl,3);
        int c4=__shfl(cl,4), c5=__shfl(cl,5), c6=__shfl(cl,6), c7=__shfl(cl,7);
        ushort4 h0 = Xi[c0 * 64 + lane];
        ushort4 h1 = Xi[c1 * 64 + lane];
        ushort4 h2 = Xi[c2 * 64 + lane];
        ushort4 h3 = Xi[c3 * 64 + lane];
        ushort4 h4 = Xi[c4 * 64 + lane];
        ushort4 h5 = Xi[c5 * 64 + lane];
        ushort4 h6 = Xi[c6 * 64 + lane];
        ushort4 h7 = Xi[c7 * 64 + lane];
        for (int j = 0; j < cnt; j += 8) {
            ushort4 g0=h0, g1=h1, g2=h2, g3=h3, g4=h4, g5=h5, g6=h6, g7=h7;
            int jn = j + 8;
            if (jn < cnt) {
                int d0=__shfl(cl,jn),   d1=__shfl(cl,jn+1), d2=__shfl(cl,jn+2), d3=__shfl(cl,jn+3);
                int d4=__shfl(cl,jn+4), d5=__shfl(cl,jn+5), d6=__shfl(cl,jn+6), d7=__shfl(cl,jn+7);
                h0 = Xi[d0 * 64 + lane];
                h1 = Xi[d1 * 64 + lane];
                h2 = Xi[d2 * 64 + lane];
                h3 = Xi[d3 * 64 + lane];
                h4 = Xi[d4 * 64 + lane];
                h5 = Xi[d5 * 64 + lane];
                h6 = Xi[d6 * 64 + lane];
                h7 = Xi[d7 * 64 + lane];
            }
            float v0=__shfl(vl,j),   v1=__shfl(vl,j+1), v2=__shfl(vl,j+2), v3=__shfl(vl,j+3);
            float v4=__shfl(vl,j+4), v5=__shfl(vl,j+5), v6=__shfl(vl,j+6), v7=__shfl(vl,j+7);
            ax += v0*bf2f(g0.x); ay += v0*bf2f(g0.y); az += v0*bf2f(g0.z); aw += v0*bf2f(g0.w);
            ax += v1*bf2f(g1.x); ay += v1*bf2f(g1.y); az += v1*bf2f(g1.z); aw += v1*bf2f(g1.w);
            ax += v2*bf2f(g2.x); ay += v2*bf2f(g2.y); az += v2*bf2f(g2.z); aw += v2*bf2f(g2.w);
            ax += v3*bf2f(g3.x); ay += v3*bf2f(g3.y); az += v3*bf2f(g3.z); aw += v3*bf2f(g3.w);
            ax += v4*bf2f(g4.x); ay += v4*bf2f(g4.y); az += v4*bf2f(g4.z); aw += v4*bf2f(g4.w);
            ax += v5*bf2f(g5.x); ay += v5*bf2f(g5.y); az += v5*bf2f(g5.z); aw += v5*bf2f(g5.w);
            ax += v6*bf2f(g6.x); ay += v6*bf2f(g6.y); az += v6*bf2f(g6.z); aw += v6*bf2f(g6.w);
            ax += v7*bf2f(g7.x); ay += v7*bf2f(g7.y); az += v7*bf2f(g7.z); aw += v7*bf2f(g7.w);
        }
    }
    float4 r; r.x = ax; r.y = ay; r.z = az; r.w = aw;
    return r;
}

// MODE 1: Xout = L*Xin ; MODE 2: Xout = 2*L*Xin - Xprev   (bf16 in/out, fp32 acc)
template <int MODE>
__global__ __launch_bounds__(256) void spmm_kernel(
        const int* __restrict__ row_ptr, const int2* __restrict__ cv,
        const u16* __restrict__ Xin, const u16* __restrict__ Xprev,
        u16* __restrict__ Xout, int M) {
    int lane = threadIdx.x & 63, wid = threadIdx.x >> 6;
    int m = blockIdx.x * 4 + wid;
    if (m >= M) return;
    int start = row_ptr[m], end = row_ptr[m + 1];
    float4 acc = gather_row_bf(cv, start, end, (const ushort4*)Xin, lane);
    ushort4 o;
    if (MODE == 1) {
        o.x = f2bf(acc.x); o.y = f2bf(acc.y); o.z = f2bf(acc.z); o.w = f2bf(acc.w);
    } else {
        ushort4 p = ((const ushort4*)Xprev)[m * 64 + lane];
        o.x = f2bf(2.f * acc.x - bf2f(p.x));
        o.y = f2bf(2.f * acc.y - bf2f(p.y));
        o.z = f2bf(2.f * acc.z - bf2f(p.z));
        o.w = f2bf(2.f * acc.w - bf2f(p.w));
    }
    ((ushort4*)Xout)[m * 64 + lane] = o;
}

// ---------------------------------------------------------------- einsum
// y[b,o,m] = bias[o] + sum_k sum_ci th[k][ci][o] * Xk[m][b*32+ci], all 8 b.
// Block = 256 threads, 8 rows; thread: rA=tid&3 (+rB=rA+4), og=(tid>>2)&7,
// bsel=tid>>5 (batch 0..7). 2 rows/thread amortizes theta LDS reads.
// k-loop NOT unrolled (r3/r5 lesson); staging prefetched one k ahead (T14).
__global__ __launch_bounds__(256, 4) void einsum_kernel(
        const u16* __restrict__ Xbase,    // X0..X3 contiguous, stride MCu
        size_t MCu,
        const float* __restrict__ th_t, const float* __restrict__ bias,
        float* __restrict__ y, int M) {
    __shared__ __align__(16) float th_lds[KCH * CIN * COUT];   // 32 KB
    __shared__ __align__(16) u16 x_lds[8][264];                // 4.1 KB (per-k reuse)

    int tid = threadIdx.x;
    for (int i = tid * 4; i < KCH * CIN * COUT; i += 1024)
        *(float4*)&th_lds[i] = *(const float4*)&th_t[i];

    int m0 = blockIdx.x * 8;
    int sr = tid >> 5, sf = tid & 31;        // staging: row sr, 16B piece sf
    int sm = m0 + sr;

    int rA = tid & 3, rB = rA + 4;
    int og = (tid >> 2) & 7;
    int bsel = tid >> 5;                     // wave-uniform pairs
    int mA = m0 + rA, mB = m0 + rB;

    uint4 sv = {0u, 0u, 0u, 0u};
    if (sm < M) sv = *(const uint4*)&Xbase[(size_t)sm * F_DIM + sf * 8];

    float accA[8] = {0.f,0.f,0.f,0.f,0.f,0.f,0.f,0.f};
    float accB[8] = {0.f,0.f,0.f,0.f,0.f,0.f,0.f,0.f};

    #pragma unroll 1
    for (int k = 0; k < KCH; k++) {
        __syncthreads();                     // prior accum reads of x_lds done
        *(uint4*)&x_lds[sr][sf * 8] = sv;
        if (k < 3) {                         // prefetch next k (hidden under accum)
            const u16* Xn = Xbase + (size_t)(k + 1) * MCu;
            uint4 nv = {0u, 0u, 0u, 0u};
            if (sm < M) nv = *(const uint4*)&Xn[(size_t)sm * F_DIM + sf * 8];
            sv = nv;
        }
        __syncthreads();                     // staging (and th for k=0) visible
        const float* thk = &th_lds[k * CIN * COUT];
        #pragma unroll
        for (int ci4 = 0; ci4 < 8; ci4++) {
            ushort4 ua = *(const ushort4*)&x_lds[rA][bsel * 32 + ci4 * 4];
            ushort4 ub = *(const ushort4*)&x_lds[rB][bsel * 32 + ci4 * 4];
            float fa[4] = {bf2f(ua.x), bf2f(ua.y), bf2f(ua.z), bf2f(ua.w)};
            float fb[4] = {bf2f(ub.x), bf2f(ub.y), bf2f(ub.z), bf2f(ub.w)};
            #pragma unroll
            for (int c = 0; c < 4; c++) {
                const float* tp = &thk[(ci4 * 4 + c) * COUT + og * 8];
                float4 t0 = *(const float4*)tp;
                float4 t1 = *(const float4*)(tp + 4);
                float a = fa[c], b = fb[c];
                accA[0] += a*t0.x; accA[1] += a*t0.y; accA[2] += a*t0.z; accA[3] += a*t0.w;
                accA[4] += a*t1.x; accA[5] += a*t1.y; accA[6] += a*t1.z; accA[7] += a*t1.w;
                accB[0] += b*t0.x; accB[1] += b*t0.y; accB[2] += b*t0.z; accB[3] += b*t0.w;
                accB[4] += b*t1.x; accB[5] += b*t1.y; accB[6] += b*t1.z; accB[7] += b*t1.w;
            }
        }
    }

    float4 bs0 = *(const float4*)&bias[og * 8];
    float4 bs1 = *(const float4*)&bias[og * 8 + 4];
    float bv[8] = {bs0.x, bs0.y, bs0.z, bs0.w, bs1.x, bs1.y, bs1.z, bs1.w};
    size_t obase = (size_t)(bsel * COUT + og * 8) * M;
    if (mA < M) {
        #pragma unroll
        for (int oo = 0; oo < 8; oo++)
            y[obase + (size_t)oo * M + mA] = accA[oo] + bv[oo];
    }
    if (mB < M) {
        #pragma unroll
        for (int oo = 0; oo < 8; oo++)
            y[obase + (size_t)oo * M + mB] = accB[oo] + bv[oo];
    }
}

// ---------------------------------------------------------------- launcher

extern "C" void kernel_launch(void* const* d_in, const int* in_sizes, int n_in,
                              void* d_out, int out_size, void* d_ws, size_t ws_size,
                              hipStream_t stream) {
    const float* x     = (const float*)d_in[0];
    const int*   L_row = (const int*)d_in[1];
    const int*   L_col = (const int*)d_in[2];
    const float* L_val = (const float*)d_in[3];
    const float* theta = (const float*)d_in[4];
    const float* bias  = (const float*)d_in[5];
    float* y = (float*)d_out;

    int M   = in_sizes[0] / F_DIM;   // 100000
    int NNZ = in_sizes[1];           // 1600000
    int Mpad = (M + 4 + 3) & ~3;

    // workspace: X0..X3 bf16 (M*256 u16 each, 51.2 MB), theta, CSR
    size_t MCu = (size_t)M * F_DIM;
    u16*   X0      = (u16*)d_ws;
    u16*   X1      = X0 + MCu;
    u16*   X2      = X1 + MCu;
    u16*   X3      = X2 + MCu;
    float* th_t    = (float*)(X3 + MCu);
    int*   row_ptr = (int*)(th_t + KCH * CIN * COUT);
    int*   cursor  = row_ptr + Mpad;
    int2*  cv      = (int2*)(cursor + ((M + 3) & ~3));

    // CSR build (once)
    zero_kernel<<<(M + 255) / 256, 256, 0, stream>>>(cursor, M);
    hist_kernel<<<(NNZ + 255) / 256, 256, 0, stream>>>(L_row, cursor, NNZ);
    scan_kernel<<<1, 1024, 0, stream>>>(cursor, row_ptr, M);
    scatter_kernel<<<(NNZ + 255) / 256, 256, 0, stream>>>(L_row, L_col, L_val,
                                                          cursor, cv, NNZ);
    th_prep_kernel<<<(KCH * CIN * COUT + 255) / 256, 256, 0, stream>>>(theta, th_t);

    // full-F pipeline: hot gather operand = one 51.2 MB bf16 buffer (L3-resident)
    transpose_kernel<<<dim3((M + 63) / 64, F_DIM / 64), 256, 0, stream>>>(x, X0, M);
    spmm_kernel<1><<<(M + 3) / 4, 256, 0, stream>>>(row_ptr, cv, X0, nullptr, X1, M);
    spmm_kernel<2><<<(M + 3) / 4, 256, 0, stream>>>(row_ptr, cv, X1, X0, X2, M);
    spmm_kernel<2><<<(M + 3) / 4, 256, 0, stream>>>(row_ptr, cv, X2, X1, X3, M);
    einsum_kernel<<<(M + 7) / 8, 256, 0, stream>>>(X0, MCu, th_t, bias, y, M);
}

// Round 11
// 755.505 us; speedup vs baseline: 7.6742x; 1.2751x over previous
//
#include <hip/hip_runtime.h>
#include <hip/hip_bf16.h>

typedef unsigned short u16;

#define B_DIM 8
#define CIN   32
#define COUT  64
#define KCH   4
#define F_DIM 256   // B_DIM*CIN; bf16 X rows = 512 B

using f32x4  = __attribute__((ext_vector_type(4))) float;
using bf16x8 = __attribute__((ext_vector_type(8))) short;

// bf16 helpers
__device__ __forceinline__ float bf2f(u16 u) {
    return __uint_as_float(((unsigned)u) << 16);
}
__device__ __forceinline__ u16 f2bf(float f) {
    union { __hip_bfloat16 h; u16 u; } c;
    c.h = __float2bfloat16(f);           // RNE
    return c.u;
}

// ---------------------------------------------------------------- utilities

__global__ __launch_bounds__(256) void zero_kernel(int* p, int n) {
    int i = blockIdx.x * 256 + threadIdx.x;
    if (i < n) p[i] = 0;
}

__global__ __launch_bounds__(256) void hist_kernel(const int* __restrict__ L_row,
                                                   int* __restrict__ cnt, int nnz) {
    int i = blockIdx.x * 256 + threadIdx.x;
    if (i < nnz) atomicAdd(&cnt[L_row[i]], 1);
}

// single-block exclusive scan, 8 elements/thread.
__global__ __launch_bounds__(1024) void scan_kernel(int* __restrict__ cursor,
                                                    int* __restrict__ row_ptr, int M) {
    __shared__ int wsum[16];
    __shared__ int sbase_s;
    int tid = threadIdx.x, lane = tid & 63, wid = tid >> 6;
    if (tid == 0) sbase_s = 0;
    __syncthreads();
    int nchunk = (M + 8191) / 8192;
    for (int ch = 0; ch < nchunk; ch++) {
        int i0 = ch * 8192 + tid * 8;
        int v[8];
        if (i0 + 8 <= M) {
            int4 a = *(const int4*)&cursor[i0];
            int4 b = *(const int4*)&cursor[i0 + 4];
            v[0]=a.x; v[1]=a.y; v[2]=a.z; v[3]=a.w;
            v[4]=b.x; v[5]=b.y; v[6]=b.z; v[7]=b.w;
        } else {
            #pragma unroll
            for (int t = 0; t < 8; t++) v[t] = (i0 + t < M) ? cursor[i0 + t] : 0;
        }
        int s = 0;
        #pragma unroll
        for (int t = 0; t < 8; t++) { int tmp = v[t]; v[t] = s; s += tmp; }
        int sc = s;
        #pragma unroll
        for (int d = 1; d < 64; d <<= 1) {
            int t = __shfl_up(sc, d);
            if (lane >= d) sc += t;
        }
        if (lane == 63) wsum[wid] = sc;
        __syncthreads();
        if (wid == 0) {
            int w = (lane < 16) ? wsum[lane] : 0;
            #pragma unroll
            for (int d = 1; d < 16; d <<= 1) {
                int t = __shfl_up(w, d);
                if (lane >= d) w += t;
            }
            if (lane < 16) wsum[lane] = w;
        }
        __syncthreads();
        int base = sbase_s + ((wid > 0) ? wsum[wid - 1] : 0) + (sc - s);
        #pragma unroll
        for (int t = 0; t < 8; t++) {
            int idx = i0 + t;
            if (idx < M) { int e = base + v[t]; row_ptr[idx] = e; cursor[idx] = e; }
        }
        __syncthreads();
        if (tid == 0) sbase_s += wsum[15];
        __syncthreads();
    }
    if (tid == 0) row_ptr[M] = sbase_s;
}

// pack (col, val) int2 pairs in CSR order
__global__ __launch_bounds__(256) void scatter_kernel(
        const int* __restrict__ L_row, const int* __restrict__ L_col,
        const float* __restrict__ L_val,
        int* __restrict__ cursor, int2* __restrict__ cv, int nnz) {
    int i = blockIdx.x * 256 + threadIdx.x;
    if (i < nnz) {
        int r = L_row[i];
        int p = atomicAdd(&cursor[r], 1);
        int2 e;
        e.x = L_col[i];
        e.y = __float_as_int(L_val[i]);
        cv[p] = e;
    }
}

// theta (COUT,CIN,K) fp32 -> thB bf16 [k][ot][o'][ci]  (B-fragment friendly)
__global__ __launch_bounds__(256) void th_prep2_kernel(const float* __restrict__ theta,
                                                       u16* __restrict__ thB) {
    int idx = blockIdx.x * 256 + threadIdx.x;   // 8192 total
    if (idx < KCH * CIN * COUT) {
        int ci = idx & 31;
        int op = (idx >> 5) & 15;
        int ot = (idx >> 9) & 3;
        int k  = idx >> 11;
        int o  = ot * 16 + op;
        thB[idx] = f2bf(theta[(o * CIN + ci) * KCH + k]);
    }
}

// x (256,M) fp32 -> X0 (M,256) bf16: 64x64 LDS tile transpose, 4 f-blocks
__global__ __launch_bounds__(256) void transpose_kernel(const float* __restrict__ x,
                                                        u16* __restrict__ X0c, int M) {
    __shared__ float tile[64][65];
    int tid = threadIdx.x;
    int ml = tid & 63;
    int fl0 = tid >> 6;               // 0..3
    int m0 = blockIdx.x * 64;
    int fb = blockIdx.y * 64;
    #pragma unroll 4
    for (int ff = fl0; ff < 64; ff += 4) {
        int m = m0 + ml;
        tile[ff][ml] = (m < M) ? x[(size_t)(fb + ff) * M + m] : 0.f;
    }
    __syncthreads();
    int fl = tid & 63;
    #pragma unroll 4
    for (int mm = fl0; mm < 64; mm += 4) {
        int m = m0 + mm;
        if (m < M) X0c[(size_t)m * F_DIM + fb + fl] = f2bf(tile[fl][mm]);
    }
}

// ---------------------------------------------------------------- SpMM core
// One wave gathers one CSR row over 256 bf16: lane owns ushort4 (8 B) at
// Xi[c*64 + lane]. 8-deep software pipeline (4 KB in flight per wave).
__device__ __forceinline__ float4 gather_row_bf(const int2* __restrict__ cv,
                                                int start, int end,
                                                const ushort4* __restrict__ Xi,
                                                int lane) {
    float ax = 0.f, ay = 0.f, az = 0.f, aw = 0.f;
    for (int base = start; base < end; base += 64) {
        int e = base + lane;
        int cl = 0; float vl = 0.f;
        if (e < end) { int2 p = cv[e]; cl = p.x; vl = __int_as_float(p.y); }
        int cnt = min(64, end - base);
        int c0=__shfl(cl,0), c1=__shfl(cl,1), c2=__shfl(cl,2), c3=__shfl(cl,3);
        int c4=__shfl(cl,4), c5=__shfl(cl,5), c6=__shfl(cl,6), c7=__shfl(cl,7);
        ushort4 h0 = Xi[c0 * 64 + lane];
        ushort4 h1 = Xi[c1 * 64 + lane];
        ushort4 h2 = Xi[c2 * 64 + lane];
        ushort4 h3 = Xi[c3 * 64 + lane];
        ushort4 h4 = Xi[c4 * 64 + lane];
        ushort4 h5 = Xi[c5 * 64 + lane];
        ushort4 h6 = Xi[c6 * 64 + lane];
        ushort4 h7 = Xi[c7 * 64 + lane];
        for (int j = 0; j < cnt; j += 8) {
            ushort4 g0=h0, g1=h1, g2=h2, g3=h3, g4=h4, g5=h5, g6=h6, g7=h7;
            int jn = j + 8;
            if (jn < cnt) {
                int d0=__shfl(cl,jn),   d1=__shfl(cl,jn+1), d2=__shfl(cl,jn+2), d3=__shfl(cl,jn+3);
                int d4=__shfl(cl,jn+4), d5=__shfl(cl,jn+5), d6=__shfl(cl,jn+6), d7=__shfl(cl,jn+7);
                h0 = Xi[d0 * 64 + lane];
                h1 = Xi[d1 * 64 + lane];
                h2 = Xi[d2 * 64 + lane];
                h3 = Xi[d3 * 64 + lane];
                h4 = Xi[d4 * 64 + lane];
                h5 = Xi[d5 * 64 + lane];
                h6 = Xi[d6 * 64 + lane];
                h7 = Xi[d7 * 64 + lane];
            }
            float v0=__shfl(vl,j),   v1=__shfl(vl,j+1), v2=__shfl(vl,j+2), v3=__shfl(vl,j+3);
            float v4=__shfl(vl,j+4), v5=__shfl(vl,j+5), v6=__shfl(vl,j+6), v7=__shfl(vl,j+7);
            ax += v0*bf2f(g0.x); ay += v0*bf2f(g0.y); az += v0*bf2f(g0.z); aw += v0*bf2f(g0.w);
            ax += v1*bf2f(g1.x); ay += v1*bf2f(g1.y); az += v1*bf2f(g1.z); aw += v1*bf2f(g1.w);
            ax += v2*bf2f(g2.x); ay += v2*bf2f(g2.y); az += v2*bf2f(g2.z); aw += v2*bf2f(g2.w);
            ax += v3*bf2f(g3.x); ay += v3*bf2f(g3.y); az += v3*bf2f(g3.z); aw += v3*bf2f(g3.w);
            ax += v4*bf2f(g4.x); ay += v4*bf2f(g4.y); az += v4*bf2f(g4.z); aw += v4*bf2f(g4.w);
            ax += v5*bf2f(g5.x); ay += v5*bf2f(g5.y); az += v5*bf2f(g5.z); aw += v5*bf2f(g5.w);
            ax += v6*bf2f(g6.x); ay += v6*bf2f(g6.y); az += v6*bf2f(g6.z); aw += v6*bf2f(g6.w);
            ax += v7*bf2f(g7.x); ay += v7*bf2f(g7.y); az += v7*bf2f(g7.z); aw += v7*bf2f(g7.w);
        }
    }
    float4 r; r.x = ax; r.y = ay; r.z = az; r.w = aw;
    return r;
}

// MODE 1: Xout = L*Xin ; MODE 2: Xout = 2*L*Xin - Xprev   (bf16 in/out, fp32 acc)
template <int MODE>
__global__ __launch_bounds__(256) void spmm_kernel(
        const int* __restrict__ row_ptr, const int2* __restrict__ cv,
        const u16* __restrict__ Xin, const u16* __restrict__ Xprev,
        u16* __restrict__ Xout, int M) {
    int lane = threadIdx.x & 63, wid = threadIdx.x >> 6;
    int m = blockIdx.x * 4 + wid;
    if (m >= M) return;
    int start = row_ptr[m], end = row_ptr[m + 1];
    float4 acc = gather_row_bf(cv, start, end, (const ushort4*)Xin, lane);
    ushort4 o;
    if (MODE == 1) {
        o.x = f2bf(acc.x); o.y = f2bf(acc.y); o.z = f2bf(acc.z); o.w = f2bf(acc.w);
    } else {
        ushort4 p = ((const ushort4*)Xprev)[m * 64 + lane];
        o.x = f2bf(2.f * acc.x - bf2f(p.x));
        o.y = f2bf(2.f * acc.y - bf2f(p.y));
        o.z = f2bf(2.f * acc.z - bf2f(p.z));
        o.w = f2bf(2.f * acc.w - bf2f(p.w));
    }
    ((ushort4*)Xout)[m * 64 + lane] = o;
}

// ---------------------------------------------------------------- MFMA einsum
// y[b, o, m] = bias[o] + sum_k sum_ci th[k][ci][o] * Xk[m][b*32+ci]
// Per wave: 16 m-rows; per b: K=32 MFMA per cheb-k accumulated over 4 k's
// into 4 o-tiles of 16. A-frag: lane reads Xk[m0w + (l&15)][b*32 + (l>>4)*8 .. +8]
// (16 B, global; X is L3-resident). B-frags (theta, 16 total) hoisted into regs.
// Same k-index mapping used for A and B -> correct under any HW k-permutation.
// C/D layout (verified, m89): col = l&15 (o), row = (l>>4)*4 + j (m) -> f32x4
// store of 4 consecutive m; one full 64-B y line per wave per o-plane.
// b-loop unroll 1 (r3/r5 lesson: never merge acc live ranges across phases).
__global__ __launch_bounds__(256, 2) void einsum_mfma_kernel(
        const u16* __restrict__ Xbase,    // X0..X3 contiguous, stride MCu
        size_t MCu,
        const u16* __restrict__ thB, const float* __restrict__ bias,
        float* __restrict__ y, int M) {
    int tid = threadIdx.x;
    int lane = tid & 63, w = tid >> 6;
    int m0w = blockIdx.x * 64 + w * 16;          // wave's 16-row tile (M % 16 == 0)
    if (m0w >= M) return;

    int col = lane & 15;        // A-row / B-col / D-col index
    int kg  = lane >> 4;        // k-group (0..3): k-elems kg*8 .. +8

    // hoist 16 B-fragments: (k, ot)
    bf16x8 Bf[16];
    #pragma unroll
    for (int kk = 0; kk < 16; kk++) {
        // thB[((k*4+ot)*16 + col)*32 + kg*8], kk = k*4+ot
        Bf[kk] = *(const bf16x8*)&thB[(kk * 16 + col) * 32 + kg * 8];
    }
    // hoist bias per o-tile
    float bv[4];
    #pragma unroll
    for (int ot = 0; ot < 4; ot++) bv[ot] = bias[ot * 16 + col];

    const u16* xrow = Xbase + (size_t)(m0w + col) * F_DIM + kg * 8;

    #pragma unroll 1
    for (int b = 0; b < B_DIM; b++) {
        f32x4 acc0 = {0.f, 0.f, 0.f, 0.f};
        f32x4 acc1 = {0.f, 0.f, 0.f, 0.f};
        f32x4 acc2 = {0.f, 0.f, 0.f, 0.f};
        f32x4 acc3 = {0.f, 0.f, 0.f, 0.f};
        #pragma unroll
        for (int k = 0; k < KCH; k++) {
            bf16x8 A = *(const bf16x8*)(xrow + (size_t)k * MCu + b * CIN);
            acc0 = __builtin_amdgcn_mfma_f32_16x16x32_bf16(A, Bf[k * 4 + 0], acc0, 0, 0, 0);
            acc1 = __builtin_amdgcn_mfma_f32_16x16x32_bf16(A, Bf[k * 4 + 1], acc1, 0, 0, 0);
            acc2 = __builtin_amdgcn_mfma_f32_16x16x32_bf16(A, Bf[k * 4 + 2], acc2, 0, 0, 0);
            acc3 = __builtin_amdgcn_mfma_f32_16x16x32_bf16(A, Bf[k * 4 + 3], acc3, 0, 0, 0);
        }
        int mrow = m0w + kg * 4;                 // 4 consecutive m (j = 0..3)
        #pragma unroll
        for (int ot = 0; ot < 4; ot++) {
            f32x4 a = (ot == 0) ? acc0 : (ot == 1) ? acc1 : (ot == 2) ? acc2 : acc3;
            f32x4 o4;
            o4[0] = a[0] + bv[ot]; o4[1] = a[1] + bv[ot];
            o4[2] = a[2] + bv[ot]; o4[3] = a[3] + bv[ot];
            size_t off = (size_t)(b * COUT + ot * 16 + col) * M + mrow;
            __builtin_nontemporal_store(o4, (f32x4*)&y[off]);
        }
    }
}

// ---------------------------------------------------------------- launcher

extern "C" void kernel_launch(void* const* d_in, const int* in_sizes, int n_in,
                              void* d_out, int out_size, void* d_ws, size_t ws_size,
                              hipStream_t stream) {
    const float* x     = (const float*)d_in[0];
    const int*   L_row = (const int*)d_in[1];
    const int*   L_col = (const int*)d_in[2];
    const float* L_val = (const float*)d_in[3];
    const float* theta = (const float*)d_in[4];
    const float* bias  = (const float*)d_in[5];
    float* y = (float*)d_out;

    int M   = in_sizes[0] / F_DIM;   // 100000
    int NNZ = in_sizes[1];           // 1600000
    int Mpad = (M + 4 + 3) & ~3;

    // workspace: X0..X3 bf16 (M*256 u16 each, 51.2 MB), thB bf16, CSR
    size_t MCu = (size_t)M * F_DIM;
    u16*   X0      = (u16*)d_ws;
    u16*   X1      = X0 + MCu;
    u16*   X2      = X1 + MCu;
    u16*   X3      = X2 + MCu;
    u16*   thB     = X3 + MCu;                      // 8192 u16
    int*   row_ptr = (int*)(thB + KCH * CIN * COUT);
    int*   cursor  = row_ptr + Mpad;
    int2*  cv      = (int2*)(cursor + ((M + 3) & ~3));

    // CSR build (once)
    zero_kernel<<<(M + 255) / 256, 256, 0, stream>>>(cursor, M);
    hist_kernel<<<(NNZ + 255) / 256, 256, 0, stream>>>(L_row, cursor, NNZ);
    scan_kernel<<<1, 1024, 0, stream>>>(cursor, row_ptr, M);
    scatter_kernel<<<(NNZ + 255) / 256, 256, 0, stream>>>(L_row, L_col, L_val,
                                                          cursor, cv, NNZ);
    th_prep2_kernel<<<(KCH * CIN * COUT + 255) / 256, 256, 0, stream>>>(theta, thB);

    // full-F pipeline: hot gather operand = one 51.2 MB bf16 buffer (L3-resident)
    transpose_kernel<<<dim3((M + 63) / 64, F_DIM / 64), 256, 0, stream>>>(x, X0, M);
    spmm_kernel<1><<<(M + 3) / 4, 256, 0, stream>>>(row_ptr, cv, X0, nullptr, X1, M);
    spmm_kernel<2><<<(M + 3) / 4, 256, 0, stream>>>(row_ptr, cv, X1, X0, X2, M);
    spmm_kernel<2><<<(M + 3) / 4, 256, 0, stream>>>(row_ptr, cv, X2, X1, X3, M);
    einsum_mfma_kernel<<<(M + 63) / 64, 256, 0, stream>>>(X0, MCu, thB, bias, y, M);
}